// Round 3
// baseline (2057.482 us; speedup 1.0000x reference)
//
#include <hip/hip_runtime.h>

typedef unsigned short u16;
typedef __attribute__((ext_vector_type(8))) short short8;
typedef __attribute__((ext_vector_type(4))) float f32x4;

#define BATCH 256
#define N0    512
#define N1    2048
#define NIN   4096
#define TSTEPS 60

static __device__ __forceinline__ f32x4 MFMA(short8 a, short8 b, f32x4 c) {
    return __builtin_amdgcn_mfma_f32_16x16x32_bf16(a, b, c, 0, 0, 0);
}

// x = hi + lo (both bf16, truncation split). Residual ~2^-16 relative.
static __device__ __forceinline__ void split1(float x, u16* __restrict__ hp, u16* __restrict__ lp) {
    unsigned bx = __float_as_uint(x);
    *hp = (u16)(bx >> 16);
    float lf = x - __uint_as_float(bx & 0xFFFF0000u);
    *lp = (u16)(__float_as_uint(lf) >> 16);
}

// load 8 contiguous f32 and produce hi/lo bf16x8 fragments (bit-packing)
static __device__ __forceinline__ void split8(const float* __restrict__ p, short8& h, short8& l) {
    const float4 x0 = *(const float4*)p;
    const float4 x1 = *(const float4*)(p + 4);
    float xs[8] = {x0.x, x0.y, x0.z, x0.w, x1.x, x1.y, x1.z, x1.w};
    union { short8 v; unsigned u[4]; } H, L;
    #pragma unroll
    for (int j = 0; j < 4; ++j) {
        unsigned ba = __float_as_uint(xs[2*j]);
        unsigned bb = __float_as_uint(xs[2*j+1]);
        H.u[j] = (ba >> 16) | (bb & 0xFFFF0000u);
        float la = xs[2*j]   - __uint_as_float(ba & 0xFFFF0000u);
        float lb = xs[2*j+1] - __uint_as_float(bb & 0xFFFF0000u);
        L.u[j] = (__float_as_uint(la) >> 16) | (__float_as_uint(lb) & 0xFFFF0000u);
    }
    h = H.v; l = L.v;
}

static __device__ __forceinline__ float clamp01(float v) {
    return fminf(fmaxf(v, 0.0f), 1.0f);
}

// -------- prep: split weights / data / initial states into bf16 hi/lo --------
__global__ __launch_bounds__(256) void prep_kernel(
    const float* __restrict__ w0, const float* __restrict__ w1,
    const float* __restrict__ data,
    const float* __restrict__ s0, const float* __restrict__ s1,
    u16* __restrict__ w0h, u16* __restrict__ w0l,
    u16* __restrict__ w1h, u16* __restrict__ w1l,
    u16* __restrict__ dh,  u16* __restrict__ dl,
    float* __restrict__ s0f, float* __restrict__ s1f,
    u16* __restrict__ s0h, u16* __restrict__ s0l,
    u16* __restrict__ s1h, u16* __restrict__ s1l)
{
    const int tid = blockIdx.x * blockDim.x + threadIdx.x;
    const int nth = gridDim.x * blockDim.x;
    const int NW = N0 * N1;  // 1048576 == BATCH*NIN too
    for (int i = tid; i < NW; i += nth) {
        split1(w0[i],   &w0h[i], &w0l[i]);
        split1(w1[i],   &w1h[i], &w1l[i]);
        split1(data[i], &dh[i],  &dl[i]);
    }
    for (int i = tid; i < BATCH * N0; i += nth) {
        float v = s0[i]; s0f[i] = v; split1(v, &s0h[i], &s0l[i]);
    }
    for (int i = tid; i < BATCH * N1; i += nth) {
        float v = s1[i]; s1f[i] = v; split1(v, &s1h[i], &s1l[i]);
    }
}

// -------- inp1 partials: data @ w2^T, K=4096 split into 4 chunks --------
// 2048 WGs: chunk = bid>>9, tile = bid&511 (8 m-tiles x 64 n-tiles of 32x32),
// each wave owns one 16x16 quadrant.
__global__ __launch_bounds__(256, 8) void inp1_kernel(
    const u16* __restrict__ dh, const u16* __restrict__ dl,
    const float* __restrict__ w2,
    float* __restrict__ partial)   // [4][256][2048]
{
    const int wave = threadIdx.x >> 6, lane = threadIdx.x & 63;
    const int lrow = lane & 15, lk8 = (lane >> 4) << 3, lr4 = (lane >> 4) << 2;
    const int chunk = (int)blockIdx.x >> 9;
    const int t = (int)blockIdx.x & 511;
    const int mbase = (t >> 6) * 32 + (wave >> 1) * 16;
    const int nbase = (t & 63) * 32 + (wave & 1) * 16;
    const int kbase = chunk * 1024;

    f32x4 acc0 = {}, acc1 = {}, acc2 = {};
    const size_t arow = (size_t)(mbase + lrow) * NIN + kbase;
    const size_t brow = (size_t)(nbase + lrow) * NIN + kbase;
    #pragma unroll 4
    for (int k0 = 0; k0 < 1024; k0 += 32) {
        const int ko = k0 + lk8;
        short8 ah = *(const short8*)(dh + arow + ko);
        short8 al = *(const short8*)(dl + arow + ko);
        short8 bh, bl;
        split8(w2 + brow + ko, bh, bl);
        acc0 = MFMA(ah, bh, acc0);
        acc1 = MFMA(ah, bl, acc1);
        acc2 = MFMA(al, bh, acc2);
    }
    float* out = partial + (size_t)chunk * BATCH * N1;
    const int col = nbase + lrow;
    #pragma unroll
    for (int r = 0; r < 4; ++r) {
        const int row = mbase + lr4 + r;
        out[(size_t)row * N1 + col] = acc0[r] + acc1[r] + acc2[r];
    }
}

// -------- reduce 4 partials + bias -> inp1 --------
__global__ __launch_bounds__(256) void reduce_kernel(
    const float* __restrict__ partial, const float* __restrict__ b2,
    float* __restrict__ inp1)
{
    const int e = blockIdx.x * 256 + threadIdx.x;   // float4 index, 131072 total
    const float4* p0 = (const float4*)partial;
    const float4* p1 = p0 + (BATCH * N1 / 4);
    const float4* p2 = p1 + (BATCH * N1 / 4);
    const float4* p3 = p2 + (BATCH * N1 / 4);
    const float4 b = ((const float4*)b2)[e & (N1 / 4 - 1)];
    float4 a0 = p0[e], a1 = p1[e], a2 = p2[e], a3 = p3[e];
    float4 r;
    r.x = a0.x + a1.x + a2.x + a3.x + b.x;
    r.y = a0.y + a1.y + a2.y + a3.y + b.y;
    r.z = a0.z + a1.z + a2.z + a3.z + b.z;
    r.w = a0.w + a1.w + a2.w + a3.w + b.w;
    ((float4*)inp1)[e] = r;
}

// -------- one Euler step --------
// WGs 0..1023   : C1 = s0 @ w1^T (K=512). 16x32 tile; waves: nfrag = w&1,
//                 khalf = w>>1 (K split 2 in-WG), LDS reduce -> s1'
// WGs 1024..1535: C0 = s1 @ w0^T (K=2048). 16x16 tile; wave = K quarter
//                 (split 4 in-WG), LDS reduce -> s0'
__global__ __launch_bounds__(256, 6) void step_kernel(
    const float* __restrict__ s0f_in, const float* __restrict__ s1f_in,
    const u16* __restrict__ s0h, const u16* __restrict__ s0l,
    const u16* __restrict__ s1h, const u16* __restrict__ s1l,
    const u16* __restrict__ w0h, const u16* __restrict__ w0l,
    const u16* __restrict__ w1h, const u16* __restrict__ w1l,
    const float* __restrict__ inp1, const float* __restrict__ b0,
    float* __restrict__ s0f_out, float* __restrict__ s1f_out,
    u16* __restrict__ s0h_out, u16* __restrict__ s0l_out,
    u16* __restrict__ s1h_out, u16* __restrict__ s1l_out)
{
    __shared__ float red[4][16][32];   // C1 uses [0..1][16][32]; C0 uses [0..3][16][0..15]
    const int wg = blockIdx.x;
    const int wave = threadIdx.x >> 6, lane = threadIdx.x & 63;
    const int lrow = lane & 15, lk8 = (lane >> 4) << 3, lr4 = (lane >> 4) << 2;
    const int tid = (int)threadIdx.x;

    if (wg < 1024) {
        // ---- C1: 16 batches x 32 n1-cols, K=512 split 2 across wave pairs ----
        const int mbase = (wg >> 6) * 16;            // 16 m-tiles
        const int nbase = (wg & 63) * 32;            // 64 n-tiles (XCD class = n%8)
        const int nfrag = wave & 1, kh = wave >> 1;
        f32x4 acc0 = {}, acc1 = {}, acc2 = {};
        const size_t arow = (size_t)(mbase + lrow) * N0 + kh * 256;
        const size_t brow = (size_t)(nbase + nfrag * 16 + lrow) * N0 + kh * 256;
        #pragma unroll 4
        for (int k0 = 0; k0 < 256; k0 += 32) {
            const int ko = k0 + lk8;
            short8 ah = *(const short8*)(s0h + arow + ko);
            short8 al = *(const short8*)(s0l + arow + ko);
            short8 bh = *(const short8*)(w1h + brow + ko);
            short8 bl = *(const short8*)(w1l + brow + ko);
            acc0 = MFMA(ah, bh, acc0);
            acc1 = MFMA(ah, bl, acc1);
            acc2 = MFMA(al, bh, acc2);
        }
        #pragma unroll
        for (int r = 0; r < 4; ++r)
            red[kh][lr4 + r][nfrag * 16 + lrow] = acc0[r] + acc1[r] + acc2[r];
        __syncthreads();
        #pragma unroll
        for (int e = tid; e < 512; e += 256) {
            const int r_ = e >> 5, c_ = e & 31;
            const float sum = red[0][r_][c_] + red[1][r_][c_];
            const size_t idx = (size_t)(mbase + r_) * N1 + nbase + c_;
            float v = 0.5f * (s1f_in[idx] + inp1[idx] + sum);
            v = clamp01(v);
            s1f_out[idx] = v;
            split1(v, &s1h_out[idx], &s1l_out[idx]);
        }
    } else {
        // ---- C0: 16 batches x 16 n0-cols, K=2048 split 4 across waves ----
        const int local = wg - 1024;                 // [0,512)
        const int rowbase = (local >> 5) * 16;       // 16 row-tiles
        const int colbase = (local & 31) * 16;       // 32 col-tiles (XCD class = c%8)
        f32x4 acc0 = {}, acc1 = {}, acc2 = {};
        const size_t arow = (size_t)(rowbase + lrow) * N1 + wave * 512;
        const size_t brow = (size_t)(colbase + lrow) * N1 + wave * 512;
        #pragma unroll 4
        for (int k0 = 0; k0 < 512; k0 += 32) {
            const int ko = k0 + lk8;
            short8 ah = *(const short8*)(s1h + arow + ko);
            short8 al = *(const short8*)(s1l + arow + ko);
            short8 bh = *(const short8*)(w0h + brow + ko);
            short8 bl = *(const short8*)(w0l + brow + ko);
            acc0 = MFMA(ah, bh, acc0);
            acc1 = MFMA(ah, bl, acc1);
            acc2 = MFMA(al, bh, acc2);
        }
        #pragma unroll
        for (int r = 0; r < 4; ++r)
            red[wave][lr4 + r][lrow] = acc0[r] + acc1[r] + acc2[r];
        __syncthreads();
        {
            const int r_ = tid >> 4, c_ = tid & 15;
            const float sum = red[0][r_][c_] + red[1][r_][c_]
                            + red[2][r_][c_] + red[3][r_][c_];
            const int col = colbase + c_;
            const size_t idx = (size_t)(rowbase + r_) * N0 + col;
            float v = 0.5f * (s0f_in[idx] + sum + b0[col]);
            v = clamp01(v);
            s0f_out[idx] = v;
            split1(v, &s0h_out[idx], &s0l_out[idx]);
        }
    }
}

extern "C" void kernel_launch(void* const* d_in, const int* in_sizes, int n_in,
                              void* d_out, int out_size, void* d_ws, size_t ws_size,
                              hipStream_t stream) {
    const float* data = (const float*)d_in[0];
    const float* s0_0 = (const float*)d_in[1];
    const float* s1_0 = (const float*)d_in[2];
    const float* w0   = (const float*)d_in[3];
    const float* b0   = (const float*)d_in[4];
    const float* w1   = (const float*)d_in[5];
    const float* w2   = (const float*)d_in[6];
    const float* b2   = (const float*)d_in[7];

    char* p = (char*)d_ws;
    auto alloc = [&](size_t bytes) -> char* {
        char* r = p;
        p += (bytes + 255) & ~(size_t)255;
        return r;
    };
    u16* w0h = (u16*)alloc(N0 * N1 * sizeof(u16));
    u16* w0l = (u16*)alloc(N0 * N1 * sizeof(u16));
    u16* w1h = (u16*)alloc(N0 * N1 * sizeof(u16));
    u16* w1l = (u16*)alloc(N0 * N1 * sizeof(u16));
    u16* dh  = (u16*)alloc((size_t)BATCH * NIN * sizeof(u16));
    u16* dl  = (u16*)alloc((size_t)BATCH * NIN * sizeof(u16));
    float* partial = (float*)alloc((size_t)4 * BATCH * N1 * sizeof(float));
    float* inp1 = (float*)alloc((size_t)BATCH * N1 * sizeof(float));
    float* s0f[2], *s1f[2];
    u16 *s0h[2], *s0l[2], *s1h[2], *s1l[2];
    for (int i = 0; i < 2; ++i) {
        s0f[i] = (float*)alloc((size_t)BATCH * N0 * sizeof(float));
        s1f[i] = (float*)alloc((size_t)BATCH * N1 * sizeof(float));
        s0h[i] = (u16*)alloc((size_t)BATCH * N0 * sizeof(u16));
        s0l[i] = (u16*)alloc((size_t)BATCH * N0 * sizeof(u16));
        s1h[i] = (u16*)alloc((size_t)BATCH * N1 * sizeof(u16));
        s1l[i] = (u16*)alloc((size_t)BATCH * N1 * sizeof(u16));
    }

    prep_kernel<<<2048, 256, 0, stream>>>(w0, w1, data, s0_0, s1_0,
                                          w0h, w0l, w1h, w1l, dh, dl,
                                          s0f[0], s1f[0], s0h[0], s0l[0], s1h[0], s1l[0]);

    inp1_kernel<<<2048, 256, 0, stream>>>(dh, dl, w2, partial);
    reduce_kernel<<<BATCH * N1 / 4 / 256, 256, 0, stream>>>(partial, b2, inp1);

    float* out_s0 = (float*)d_out;
    float* out_s1 = (float*)d_out + (size_t)BATCH * N0;

    for (int t = 0; t < TSTEPS; ++t) {
        const int cur = t & 1, nxt = cur ^ 1;
        float* s0o = (t == TSTEPS - 1) ? out_s0 : s0f[nxt];
        float* s1o = (t == TSTEPS - 1) ? out_s1 : s1f[nxt];
        step_kernel<<<1536, 256, 0, stream>>>(
            s0f[cur], s1f[cur],
            s0h[cur], s0l[cur], s1h[cur], s1l[cur],
            w0h, w0l, w1h, w1l,
            inp1, b0,
            s0o, s1o,
            s0h[nxt], s0l[nxt], s1h[nxt], s1l[nxt]);
    }
}

// Round 6
// 953.528 us; speedup vs baseline: 2.1578x; 2.1578x over previous
//
#include <hip/hip_runtime.h>

typedef unsigned short u16;
typedef __attribute__((ext_vector_type(8))) short short8;
typedef __attribute__((ext_vector_type(4))) float f32x4;

#define BATCH 256
#define N0    512
#define N1    2048
#define NIN   4096
#define TSTEPS 60

static __device__ __forceinline__ f32x4 MFMA(short8 a, short8 b, f32x4 c) {
    return __builtin_amdgcn_mfma_f32_16x16x32_bf16(a, b, c, 0, 0, 0);
}

// x = hi + lo (both bf16, truncation split). Residual ~2^-16 relative.
static __device__ __forceinline__ void split1(float x, u16* __restrict__ hp, u16* __restrict__ lp) {
    unsigned bx = __float_as_uint(x);
    *hp = (u16)(bx >> 16);
    float lf = x - __uint_as_float(bx & 0xFFFF0000u);
    *lp = (u16)(__float_as_uint(lf) >> 16);
}

static __device__ __forceinline__ float clamp01(float v) {
    return fminf(fmaxf(v, 0.0f), 1.0f);
}

// Packed fragment-order index for a [R x K] operand, 16x16x32 MFMA frags.
// Tile (rt,kt) holds rows [rt*16,+16), k [kt*32,+32); lane = (row&15) | ((k>>3 & 3)<<4),
// elem j = k&7. A wave's fragment load = base + (tile*64 + lane)*8 : contiguous 1KB.
static __device__ __forceinline__ size_t apos(int row, int col, int KT) {
    return ((size_t)((row >> 4) * KT + (col >> 5)) * 64
            + (size_t)((row & 15) | (((col >> 3) & 3) << 4))) * 8 + (col & 7);
}

// -------- prep: split + fragment-pack weights / data / initial states --------
__global__ __launch_bounds__(256) void prep_kernel(
    const float* __restrict__ w0, const float* __restrict__ w1,
    const float* __restrict__ w2, const float* __restrict__ data,
    const float* __restrict__ s0, const float* __restrict__ s1,
    u16* __restrict__ w0h, u16* __restrict__ w0l,
    u16* __restrict__ w1h, u16* __restrict__ w1l,
    u16* __restrict__ w2h, u16* __restrict__ w2l,
    u16* __restrict__ dh,  u16* __restrict__ dl,
    float* __restrict__ s0f, float* __restrict__ s1f,
    u16* __restrict__ s0h, u16* __restrict__ s0l,
    u16* __restrict__ s1h, u16* __restrict__ s1l)
{
    const int tid = blockIdx.x * 256 + threadIdx.x;
    const int nth = gridDim.x * 256;
    u16 h, l;
    for (int i = tid; i < N0 * N1; i += nth) {
        split1(w0[i], &h, &l);                 // w0: [512 x 2048], KT=64 (B of C0)
        size_t p = apos(i >> 11, i & 2047, 64);
        w0h[p] = h; w0l[p] = l;
        split1(w1[i], &h, &l);                 // w1: [2048 x 512], KT=16 (B of C1)
        p = apos(i >> 9, i & 511, 16);
        w1h[p] = h; w1l[p] = l;
        split1(data[i], &h, &l);               // data: [256 x 4096], KT=128 (A of inp1)
        p = apos(i >> 12, i & 4095, 128);
        dh[p] = h; dl[p] = l;
    }
    for (int i = tid; i < N1 * NIN; i += nth) {
        split1(w2[i], &h, &l);                 // w2: [2048 x 4096], KT=128 (B of inp1)
        size_t p = apos(i >> 12, i & 4095, 128);
        w2h[p] = h; w2l[p] = l;
    }
    for (int i = tid; i < BATCH * N0; i += nth) {
        float v = s0[i]; s0f[i] = v;           // s0: [256 x 512], KT=16 (A of C1)
        split1(v, &h, &l);
        size_t p = apos(i >> 9, i & 511, 16);
        s0h[p] = h; s0l[p] = l;
    }
    for (int i = tid; i < BATCH * N1; i += nth) {
        float v = s1[i]; s1f[i] = v;           // s1: [256 x 2048], KT=64 (A of C0)
        split1(v, &h, &l);
        size_t p = apos(i >> 11, i & 2047, 64);
        s1h[p] = h; s1l[p] = l;
    }
}

// -------- inp1 partials: data @ w2^T, all-packed loads --------
// 2048 WGs x 4 waves: wave id = chunk(4) x mt(16) x nt(128); 16x16 out, K-chunk 1024.
__global__ __launch_bounds__(256) void inp1_kernel(
    const u16* __restrict__ dh, const u16* __restrict__ dl,
    const u16* __restrict__ w2h, const u16* __restrict__ w2l,
    float* __restrict__ partial)   // [4][256][2048]
{
    const int wave = threadIdx.x >> 6, lane = threadIdx.x & 63;
    const int lrow = lane & 15, lr4 = (lane >> 4) << 2;
    const int wid = (int)blockIdx.x * 4 + wave;
    const int chunk = wid >> 11, t = wid & 2047;
    const int mt = t >> 7, nt = t & 127;
    const int kt0 = chunk * 32;                // 32 k-tiles per chunk (KT=128)

    const u16* pah = dh  + ((size_t)(mt * 128 + kt0) * 64 + lane) * 8;
    const u16* pal = dl  + ((size_t)(mt * 128 + kt0) * 64 + lane) * 8;
    const u16* pbh = w2h + ((size_t)(nt * 128 + kt0) * 64 + lane) * 8;
    const u16* pbl = w2l + ((size_t)(nt * 128 + kt0) * 64 + lane) * 8;

    f32x4 acc0 = {}, acc1 = {}, acc2 = {};
    #pragma unroll 4
    for (int i = 0; i < 32; ++i) {
        short8 ah = *(const short8*)(pah + i * 512);
        short8 al = *(const short8*)(pal + i * 512);
        short8 bh = *(const short8*)(pbh + i * 512);
        short8 bl = *(const short8*)(pbl + i * 512);
        acc0 = MFMA(ah, bh, acc0);
        acc1 = MFMA(ah, bl, acc1);
        acc2 = MFMA(al, bh, acc2);
    }
    float* out = partial + (size_t)chunk * BATCH * N1;
    const int col = nt * 16 + lrow;
    #pragma unroll
    for (int r = 0; r < 4; ++r) {
        const int row = mt * 16 + lr4 + r;
        out[(size_t)row * N1 + col] = acc0[r] + acc1[r] + acc2[r];
    }
}

// -------- reduce 4 partials + bias -> inp1 --------
__global__ __launch_bounds__(256) void reduce_kernel(
    const float* __restrict__ partial, const float* __restrict__ b2,
    float* __restrict__ inp1)
{
    const int e = blockIdx.x * 256 + threadIdx.x;   // float4 index, 131072 total
    const float4* p0 = (const float4*)partial;
    const float4* p1 = p0 + (BATCH * N1 / 4);
    const float4* p2 = p1 + (BATCH * N1 / 4);
    const float4* p3 = p2 + (BATCH * N1 / 4);
    const float4 b = ((const float4*)b2)[e & (N1 / 4 - 1)];
    float4 a0 = p0[e], a1 = p1[e], a2 = p2[e], a3 = p3[e];
    float4 r;
    r.x = a0.x + a1.x + a2.x + a3.x + b.x;
    r.y = a0.y + a1.y + a2.y + a3.y + b.y;
    r.z = a0.z + a1.z + a2.z + a3.z + b.z;
    r.w = a0.w + a1.w + a2.w + a3.w + b.w;
    ((float4*)inp1)[e] = r;
}

// -------- one Euler step (all inner-loop loads packed/coalesced) --------
// WGs 0..1023   : C1 = s0 @ w1^T (K=512). 16x32 tile; waves: nfrag=w&1, kh=w>>1
//                 (K split 2), LDS reduce -> s1' (plain f32 + packed for C0-A)
// WGs 1024..1535: C0 = s1 @ w0^T (K=2048). 16x16 tile; wave = K quarter,
//                 LDS reduce -> s0' (plain f32 + packed for C1-A)
__global__ __launch_bounds__(256, 6) void step_kernel(
    const float* __restrict__ s0f_in, const float* __restrict__ s1f_in,
    const u16* __restrict__ s0h, const u16* __restrict__ s0l,
    const u16* __restrict__ s1h, const u16* __restrict__ s1l,
    const u16* __restrict__ w0h, const u16* __restrict__ w0l,
    const u16* __restrict__ w1h, const u16* __restrict__ w1l,
    const float* __restrict__ inp1, const float* __restrict__ b0,
    float* __restrict__ s0f_out, float* __restrict__ s1f_out,
    u16* __restrict__ s0h_out, u16* __restrict__ s0l_out,
    u16* __restrict__ s1h_out, u16* __restrict__ s1l_out)
{
    __shared__ float red[4][16][32];
    const int wg = blockIdx.x;
    const int wave = threadIdx.x >> 6, lane = threadIdx.x & 63;
    const int lrow = lane & 15, lr4 = (lane >> 4) << 2;
    const int tid = (int)threadIdx.x;

    if (wg < 1024) {
        // ---- C1: 16 batches x 32 n1-cols, K=512 split 2 ----
        const int mt = wg >> 6, ng = wg & 63;
        const int nfrag = wave & 1, kh = wave >> 1;
        const int nt = ng * 2 + nfrag;
        const u16* pah = s0h + ((size_t)(mt * 16 + kh * 8) * 64 + lane) * 8;
        const u16* pal = s0l + ((size_t)(mt * 16 + kh * 8) * 64 + lane) * 8;
        const u16* pbh = w1h + ((size_t)(nt * 16 + kh * 8) * 64 + lane) * 8;
        const u16* pbl = w1l + ((size_t)(nt * 16 + kh * 8) * 64 + lane) * 8;
        f32x4 acc0 = {}, acc1 = {}, acc2 = {};
        #pragma unroll 4
        for (int i = 0; i < 8; ++i) {
            short8 ah = *(const short8*)(pah + i * 512);
            short8 al = *(const short8*)(pal + i * 512);
            short8 bh = *(const short8*)(pbh + i * 512);
            short8 bl = *(const short8*)(pbl + i * 512);
            acc0 = MFMA(ah, bh, acc0);
            acc1 = MFMA(ah, bl, acc1);
            acc2 = MFMA(al, bh, acc2);
        }
        #pragma unroll
        for (int r = 0; r < 4; ++r)
            red[kh][lr4 + r][nfrag * 16 + lrow] = acc0[r] + acc1[r] + acc2[r];
        __syncthreads();
        const int mbase = mt * 16, nbase = ng * 32;
        #pragma unroll
        for (int e = tid; e < 512; e += 256) {
            const int r_ = e >> 5, c_ = e & 31;
            const int row = mbase + r_, col = nbase + c_;
            const float sum = red[0][r_][c_] + red[1][r_][c_];
            const size_t idx = (size_t)row * N1 + col;
            float v = 0.5f * (s1f_in[idx] + inp1[idx] + sum);
            v = clamp01(v);
            s1f_out[idx] = v;
            u16 h, l; split1(v, &h, &l);
            const size_t p = apos(row, col, 64);   // s1 is A of C0 (KT=64)
            s1h_out[p] = h; s1l_out[p] = l;
        }
    } else {
        // ---- C0: 16 batches x 16 n0-cols, K=2048 split 4 ----
        const int local = wg - 1024;
        const int rt = local >> 5, ct = local & 31;
        const u16* pah = s1h + ((size_t)(rt * 64 + wave * 16) * 64 + lane) * 8;
        const u16* pal = s1l + ((size_t)(rt * 64 + wave * 16) * 64 + lane) * 8;
        const u16* pbh = w0h + ((size_t)(ct * 64 + wave * 16) * 64 + lane) * 8;
        const u16* pbl = w0l + ((size_t)(ct * 64 + wave * 16) * 64 + lane) * 8;
        f32x4 acc0 = {}, acc1 = {}, acc2 = {};
        #pragma unroll 4
        for (int i = 0; i < 16; ++i) {
            short8 ah = *(const short8*)(pah + i * 512);
            short8 al = *(const short8*)(pal + i * 512);
            short8 bh = *(const short8*)(pbh + i * 512);
            short8 bl = *(const short8*)(pbl + i * 512);
            acc0 = MFMA(ah, bh, acc0);
            acc1 = MFMA(ah, bl, acc1);
            acc2 = MFMA(al, bh, acc2);
        }
        #pragma unroll
        for (int r = 0; r < 4; ++r)
            red[wave][lr4 + r][lrow] = acc0[r] + acc1[r] + acc2[r];
        __syncthreads();
        {
            const int r_ = tid >> 4, c_ = tid & 15;
            const int row = rt * 16 + r_, col = ct * 16 + c_;
            const float sum = red[0][r_][c_] + red[1][r_][c_]
                            + red[2][r_][c_] + red[3][r_][c_];
            const size_t idx = (size_t)row * N0 + col;
            float v = 0.5f * (s0f_in[idx] + sum + b0[col]);
            v = clamp01(v);
            s0f_out[idx] = v;
            u16 h, l; split1(v, &h, &l);
            const size_t p = apos(row, col, 16);   // s0 is A of C1 (KT=16)
            s0h_out[p] = h; s0l_out[p] = l;
        }
    }
}

extern "C" void kernel_launch(void* const* d_in, const int* in_sizes, int n_in,
                              void* d_out, int out_size, void* d_ws, size_t ws_size,
                              hipStream_t stream) {
    const float* data = (const float*)d_in[0];
    const float* s0_0 = (const float*)d_in[1];
    const float* s1_0 = (const float*)d_in[2];
    const float* w0   = (const float*)d_in[3];
    const float* b0   = (const float*)d_in[4];
    const float* w1   = (const float*)d_in[5];
    const float* w2   = (const float*)d_in[6];
    const float* b2   = (const float*)d_in[7];

    char* p = (char*)d_ws;
    auto alloc = [&](size_t bytes) -> char* {
        char* r = p;
        p += (bytes + 255) & ~(size_t)255;
        return r;
    };
    u16* w0h = (u16*)alloc(N0 * N1 * sizeof(u16));
    u16* w0l = (u16*)alloc(N0 * N1 * sizeof(u16));
    u16* w1h = (u16*)alloc(N0 * N1 * sizeof(u16));
    u16* w1l = (u16*)alloc(N0 * N1 * sizeof(u16));
    u16* w2h = (u16*)alloc((size_t)N1 * NIN * sizeof(u16));
    u16* w2l = (u16*)alloc((size_t)N1 * NIN * sizeof(u16));
    u16* dh  = (u16*)alloc((size_t)BATCH * NIN * sizeof(u16));
    u16* dl  = (u16*)alloc((size_t)BATCH * NIN * sizeof(u16));
    float* partial = (float*)alloc((size_t)4 * BATCH * N1 * sizeof(float));
    float* inp1 = (float*)alloc((size_t)BATCH * N1 * sizeof(float));
    float* s0f[2], *s1f[2];
    u16 *s0h[2], *s0l[2], *s1h[2], *s1l[2];
    for (int i = 0; i < 2; ++i) {
        s0f[i] = (float*)alloc((size_t)BATCH * N0 * sizeof(float));
        s1f[i] = (float*)alloc((size_t)BATCH * N1 * sizeof(float));
        s0h[i] = (u16*)alloc((size_t)BATCH * N0 * sizeof(u16));
        s0l[i] = (u16*)alloc((size_t)BATCH * N0 * sizeof(u16));
        s1h[i] = (u16*)alloc((size_t)BATCH * N1 * sizeof(u16));
        s1l[i] = (u16*)alloc((size_t)BATCH * N1 * sizeof(u16));
    }

    prep_kernel<<<2048, 256, 0, stream>>>(w0, w1, w2, data, s0_0, s1_0,
                                          w0h, w0l, w1h, w1l, w2h, w2l, dh, dl,
                                          s0f[0], s1f[0], s0h[0], s0l[0], s1h[0], s1l[0]);

    inp1_kernel<<<2048, 256, 0, stream>>>(dh, dl, w2h, w2l, partial);
    reduce_kernel<<<BATCH * N1 / 4 / 256, 256, 0, stream>>>(partial, b2, inp1);

    float* out_s0 = (float*)d_out;
    float* out_s1 = (float*)d_out + (size_t)BATCH * N0;

    for (int t = 0; t < TSTEPS; ++t) {
        const int cur = t & 1, nxt = cur ^ 1;
        float* s0o = (t == TSTEPS - 1) ? out_s0 : s0f[nxt];
        float* s1o = (t == TSTEPS - 1) ? out_s1 : s1f[nxt];
        step_kernel<<<1536, 256, 0, stream>>>(
            s0f[cur], s1f[cur],
            s0h[cur], s0l[cur], s1h[cur], s1l[cur],
            w0h, w0l, w1h, w1l,
            inp1, b0,
            s0o, s1o,
            s0h[nxt], s0l[nxt], s1h[nxt], s1l[nxt]);
    }
}